// Round 1
// baseline (405.954 us; speedup 1.0000x reference)
//
#include <hip/hip_runtime.h>
#include <stdint.h>
#include <math.h>

#define BATCH 32
#define NANCH 33600
#define N0 25600   // 160x160, stride 8
#define N1 6400    // 80x80,  stride 16
#define N2 1600    // 40x40,  stride 32
#define TOPK 1000

// Emulate numpy float32 sigmoid: e = exp(-x) correctly rounded to f32, then 1/(1+e) in f32.
__device__ __forceinline__ float sigmoid_np(float x) {
    float e = (float)::exp(-(double)x);
    return 1.0f / (1.0f + e);
}

// ---------------- Kernel 1: per-anchor score -> unique 64-bit key ----------------
// key = (score_bits << 32) | (0xFFFFFFFF - n): descending key order == descending
// score with ties broken by ascending anchor index (jax.lax.top_k semantics).
__global__ void score_kernel(const float* __restrict__ cls0, const float* __restrict__ cls1,
                             const float* __restrict__ cls2,
                             const float* __restrict__ obj0, const float* __restrict__ obj1,
                             const float* __restrict__ obj2,
                             unsigned long long* __restrict__ keys) {
    int n = blockIdx.x * blockDim.x + threadIdx.x;
    int b = blockIdx.y;
    if (n >= NANCH) return;
    const float* cp; const float* op; int nl;
    if (n < N0)            { cp = cls0 + (size_t)b * N0; op = obj0 + (size_t)b * N0; nl = n; }
    else if (n < N0 + N1)  { cp = cls1 + (size_t)b * N1; op = obj1 + (size_t)b * N1; nl = n - N0; }
    else                   { cp = cls2 + (size_t)b * N2; op = obj2 + (size_t)b * N2; nl = n - N0 - N1; }
    float score = sigmoid_np(cp[nl]) * sigmoid_np(op[nl]);
    unsigned long long key = ((unsigned long long)__float_as_uint(score) << 32)
                           | (unsigned long long)(0xFFFFFFFFu - (unsigned)n);
    keys[(size_t)b * NANCH + n] = key;
}

// ---------------- Kernel 2: exact top-1000 per batch (radix select + rank) -------
__global__ __launch_bounds__(1024) void select_kernel(const unsigned long long* __restrict__ keys_g,
                                                      int* __restrict__ keep) {
    const int b = blockIdx.x;
    const unsigned long long* keys = keys_g + (size_t)b * NANCH;
    __shared__ unsigned int hist[256];
    __shared__ unsigned int sh_k, sh_digit, cnt;
    __shared__ unsigned long long ckey[1024];
    const int tid = threadIdx.x;

    unsigned long long prefix = 0ULL;
    unsigned int k = TOPK;
    for (int pass = 7; pass >= 0; --pass) {
        if (tid < 256) hist[tid] = 0u;
        __syncthreads();
        const int shift = pass * 8;
        const unsigned long long prefmask =
            (pass == 7) ? 0ULL : (0xFFFFFFFFFFFFFFFFULL << (shift + 8));
        for (int i = tid; i < NANCH; i += 1024) {
            unsigned long long key = keys[i];
            if ((key & prefmask) == prefix)
                atomicAdd(&hist[(unsigned)((key >> shift) & 0xFFULL)], 1u);
        }
        __syncthreads();
        if (tid == 0) {
            unsigned cum = 0; int d = 0;
            for (int v = 255; v >= 0; --v) {
                unsigned c = hist[v];
                if (cum + c >= k) { d = v; break; }
                cum += c;
            }
            sh_digit = (unsigned)d;
            sh_k = k - cum;
        }
        __syncthreads();
        prefix |= ((unsigned long long)sh_digit) << shift;
        k = sh_k;
        __syncthreads();
    }
    // prefix == 1000th-largest key; keys are distinct -> exactly TOPK keys >= prefix.
    if (tid == 0) cnt = 0u;
    __syncthreads();
    for (int i = tid; i < NANCH; i += 1024) {
        unsigned long long key = keys[i];
        if (key >= prefix) {
            unsigned pos = atomicAdd(&cnt, 1u);
            ckey[pos] = key;
        }
    }
    __syncthreads();
    const int m = (int)cnt;  // == TOPK
    if (tid < m) {
        unsigned long long my = ckey[tid];
        int r = 0;
        for (int j = 0; j < m; ++j) r += (ckey[j] > my) ? 1 : 0;   // LDS broadcast reads
        keep[b * TOPK + r] = (int)(0xFFFFFFFFu - (unsigned)(my & 0xFFFFFFFFULL));
    }
}

// ---------------- Kernel 3: gather + decode kept rows ----------------------------
// gid -> (b, r, slot): slot 0..16 = keypoint k, slot 17 = dets row.
__global__ void emit_kernel(const int* __restrict__ keep,
                            const float* __restrict__ bbox0, const float* __restrict__ bbox1,
                            const float* __restrict__ bbox2,
                            const float* __restrict__ cls0, const float* __restrict__ cls1,
                            const float* __restrict__ cls2,
                            const float* __restrict__ obj0, const float* __restrict__ obj1,
                            const float* __restrict__ obj2,
                            const float* __restrict__ kpt0, const float* __restrict__ kpt1,
                            const float* __restrict__ kpt2,
                            const float* __restrict__ vis0, const float* __restrict__ vis1,
                            const float* __restrict__ vis2,
                            float* __restrict__ out) {
    int gid = blockIdx.x * blockDim.x + threadIdx.x;
    const int total = BATCH * TOPK * 18;
    if (gid >= total) return;
    int slot = gid % 18;
    int br   = gid / 18;
    int r = br % TOPK;
    int b = br / TOPK;
    int n = keep[b * TOPK + r];

    int nl, W, HW; float s;
    const float *bb, *cp, *op, *kp, *vp;
    if (n < N0) {
        nl = n;            W = 160; HW = N0; s = 8.f;
        bb = bbox0; cp = cls0; op = obj0; kp = kpt0; vp = vis0;
    } else if (n < N0 + N1) {
        nl = n - N0;       W = 80;  HW = N1; s = 16.f;
        bb = bbox1; cp = cls1; op = obj1; kp = kpt1; vp = vis1;
    } else {
        nl = n - N0 - N1;  W = 40;  HW = N2; s = 32.f;
        bb = bbox2; cp = cls2; op = obj2; kp = kpt2; vp = vis2;
    }
    float px = (float)(nl % W) * s;
    float py = (float)(nl / W) * s;

    if (slot == 17) {
        float bx = bb[((size_t)b * 4 + 0) * HW + nl];
        float by = bb[((size_t)b * 4 + 1) * HW + nl];
        float bw = bb[((size_t)b * 4 + 2) * HW + nl];
        float bh = bb[((size_t)b * 4 + 3) * HW + nl];
        float score = sigmoid_np(cp[(size_t)b * HW + nl]) * sigmoid_np(op[(size_t)b * HW + nl]);
        float cx = bx * s + px;
        float cy = by * s + py;
        float hw_ = expf(bw) * s * 0.5f;
        float hh  = expf(bh) * s * 0.5f;
        float* o = out + ((size_t)b * TOPK + r) * 5;
        o[0] = cx - hw_;
        o[1] = cy - hh;
        o[2] = cx + hw_;
        o[3] = cy + hh;
        o[4] = score;
    } else {
        int kk = slot;
        float xk = kp[((size_t)b * 34 + 2 * kk    ) * HW + nl];
        float yk = kp[((size_t)b * 34 + 2 * kk + 1) * HW + nl];
        float vv = vp[((size_t)b * 17 + kk        ) * HW + nl];
        float* o = out + (size_t)(BATCH * TOPK * 5) + (((size_t)b * TOPK + r) * 17 + kk) * 3;
        o[0] = xk * s + px;
        o[1] = yk * s + py;
        o[2] = sigmoid_np(vv);
    }
}

extern "C" void kernel_launch(void* const* d_in, const int* in_sizes, int n_in,
                              void* d_out, int out_size, void* d_ws, size_t ws_size,
                              hipStream_t stream) {
    const float* cls0  = (const float*)d_in[0];
    const float* cls1  = (const float*)d_in[1];
    const float* cls2  = (const float*)d_in[2];
    const float* bbox0 = (const float*)d_in[3];
    const float* bbox1 = (const float*)d_in[4];
    const float* bbox2 = (const float*)d_in[5];
    const float* obj0  = (const float*)d_in[6];
    const float* obj1  = (const float*)d_in[7];
    const float* obj2  = (const float*)d_in[8];
    const float* kpt0  = (const float*)d_in[9];
    const float* kpt1  = (const float*)d_in[10];
    const float* kpt2  = (const float*)d_in[11];
    const float* vis0  = (const float*)d_in[12];
    const float* vis1  = (const float*)d_in[13];
    const float* vis2  = (const float*)d_in[14];
    float* out = (float*)d_out;

    unsigned long long* keys = (unsigned long long*)d_ws;
    int* keep = (int*)((char*)d_ws + (size_t)BATCH * NANCH * sizeof(unsigned long long));

    dim3 g1((NANCH + 255) / 256, BATCH);
    score_kernel<<<g1, 256, 0, stream>>>(cls0, cls1, cls2, obj0, obj1, obj2, keys);

    select_kernel<<<BATCH, 1024, 0, stream>>>(keys, keep);

    const int total = BATCH * TOPK * 18;
    emit_kernel<<<(total + 255) / 256, 256, 0, stream>>>(keep,
        bbox0, bbox1, bbox2, cls0, cls1, cls2, obj0, obj1, obj2,
        kpt0, kpt1, kpt2, vis0, vis1, vis2, out);
}

// Round 2
// 299.615 us; speedup vs baseline: 1.3549x; 1.3549x over previous
//
#include <hip/hip_runtime.h>
#include <stdint.h>
#include <math.h>

#define BATCH 32
#define NANCH 33600
#define N0 25600   // 160x160, stride 8
#define N1 6400    // 80x80,  stride 16
#define N2 1600    // 40x40,  stride 32
#define TOPK 1000
#define NBIN 4096
#define CCAP 2816

// numpy-exact float32 sigmoid: exp in double (correctly rounded to f32), then f32 divide.
__device__ __forceinline__ float sigmoid_np(float x) {
    float e = (float)::exp(-(double)x);
    return 1.0f / (1.0f + e);
}

// ------------- Kernel 1: per-anchor score S[b][n] = sigmoid(cls)*sigmoid(obj) -------------
__global__ void score_kernel(const float* __restrict__ cls0, const float* __restrict__ cls1,
                             const float* __restrict__ cls2,
                             const float* __restrict__ obj0, const float* __restrict__ obj1,
                             const float* __restrict__ obj2,
                             float* __restrict__ S) {
    int n = blockIdx.x * blockDim.x + threadIdx.x;
    int b = blockIdx.y;
    if (n >= NANCH) return;
    const float* cp; const float* op; int nl;
    if (n < N0)            { cp = cls0 + (size_t)b * N0; op = obj0 + (size_t)b * N0; nl = n; }
    else if (n < N0 + N1)  { cp = cls1 + (size_t)b * N1; op = obj1 + (size_t)b * N1; nl = n - N0; }
    else                   { cp = cls2 + (size_t)b * N2; op = obj2 + (size_t)b * N2; nl = n - N0 - N1; }
    S[(size_t)b * NANCH + n] = sigmoid_np(cp[nl]) * sigmoid_np(op[nl]);
}

// ------------- Kernel 2: exact top-1000 per batch ------------------------------------------
// Scores are in (0,1): positive fp32, so bit-pattern order == value order.
// 64-bit key = (score_bits << 32) | (0xFFFFFFFF - n): descending key order ==
// jax.lax.top_k order (descending score, ties by ascending index). Keys are unique.
__global__ __launch_bounds__(1024) void select_kernel(const float* __restrict__ S_g,
                                                      int* __restrict__ keep) {
    const int b = blockIdx.x;
    const float* S = S_g + (size_t)b * NANCH;
    __shared__ unsigned hist[NBIN];
    __shared__ unsigned scan[1024];
    __shared__ unsigned long long wbuf[TOPK];
    __shared__ unsigned long long cbuf[CCAP];
    __shared__ unsigned sh_T, sh_above, sh_d, sh_k2, wcnt, ccnt;
    const int tid = threadIdx.x;

    if (tid == 0) { wcnt = 0u; ccnt = 0u; }
    for (int i = tid; i < NBIN; i += 1024) hist[i] = 0u;
    __syncthreads();

    // ---- pass 1: histogram of score bits >> 19 (scores < 2.0 -> bin < 4096) ----
    const float4* S4 = (const float4*)S;
    const int M4 = NANCH / 4;
    for (int i = tid; i < M4; i += 1024) {
        float4 v = S4[i];
        atomicAdd(&hist[__float_as_uint(v.x) >> 19], 1u);
        atomicAdd(&hist[__float_as_uint(v.y) >> 19], 1u);
        atomicAdd(&hist[__float_as_uint(v.z) >> 19], 1u);
        atomicAdd(&hist[__float_as_uint(v.w) >> 19], 1u);
    }
    __syncthreads();

    // ---- parallel suffix scan: thread t owns bins [4t, 4t+3] ----
    unsigned s0 = hist[4 * tid + 0], s1 = hist[4 * tid + 1];
    unsigned s2 = hist[4 * tid + 2], s3 = hist[4 * tid + 3];
    unsigned tot = s0 + s1 + s2 + s3;
    scan[tid] = tot;
    __syncthreads();
    for (int off = 1; off < 1024; off <<= 1) {
        unsigned v = scan[tid] + ((tid + off < 1024) ? scan[tid + off] : 0u);
        __syncthreads();
        scan[tid] = v;
        __syncthreads();
    }
    unsigned excl = scan[tid] - tot;  // keys in bins > 4t+3
    // find threshold bin T: largest j with count(bins >= j) >= TOPK
    {
        unsigned a3 = excl,        f3 = excl + s3;
        unsigned a2 = f3,          f2 = f3 + s2;
        unsigned a1 = f2,          f1 = f2 + s1;
        unsigned a0 = f1,          f0 = f1 + s0;
        if (a3 < TOPK && f3 >= TOPK) { sh_T = 4u * tid + 3u; sh_above = a3; }
        if (a2 < TOPK && f2 >= TOPK) { sh_T = 4u * tid + 2u; sh_above = a2; }
        if (a1 < TOPK && f1 >= TOPK) { sh_T = 4u * tid + 1u; sh_above = a1; }
        if (a0 < TOPK && f0 >= TOPK) { sh_T = 4u * tid + 0u; sh_above = a0; }
    }
    __syncthreads();
    const unsigned T = sh_T;
    const unsigned above = sh_above;        // strict winners (bins > T), < TOPK
    const unsigned need = TOPK - above;     // to take from boundary bin T

    // ---- pass 2: collect strict winners + boundary candidates ----
    for (int i = tid; i < M4; i += 1024) {
        float4 v = S4[i];
        float c[4] = {v.x, v.y, v.z, v.w};
        #pragma unroll
        for (int q = 0; q < 4; ++q) {
            unsigned u = __float_as_uint(c[q]);
            unsigned bin = u >> 19;
            if (bin >= T) {
                unsigned n = (unsigned)(4 * i + q);
                unsigned long long key = ((unsigned long long)u << 32)
                                       | (unsigned long long)(0xFFFFFFFFu - n);
                if (bin > T) {
                    unsigned p = atomicAdd(&wcnt, 1u);
                    wbuf[p] = key;
                } else {
                    unsigned p = atomicAdd(&ccnt, 1u);
                    if (p < CCAP) cbuf[p] = key;
                }
            }
        }
    }
    __syncthreads();

    if (ccnt <= CCAP) {
        // ---- fast path: rank winners among themselves, candidates among themselves ----
        const int W = (int)wcnt;   // == above
        if (tid < W) {
            unsigned long long my = wbuf[tid];
            int r = 0;
            for (int j = 0; j < W; ++j) r += (wbuf[j] > my) ? 1 : 0;  // LDS broadcast
            keep[b * TOPK + r] = (int)(0xFFFFFFFFu - (unsigned)(my & 0xFFFFFFFFULL));
        }
        const int C = (int)ccnt;
        if (tid < C) {
            unsigned long long my = cbuf[tid];
            int r = 0;
            for (int j = 0; j < C; ++j) r += (cbuf[j] > my) ? 1 : 0;
            if (r < (int)need)
                keep[b * TOPK + W + r] = (int)(0xFFFFFFFFu - (unsigned)(my & 0xFFFFFFFFULL));
        }
    } else {
        // ---- fallback (overflow; not expected): full 8x8-bit radix select ----
        unsigned long long prefix = 0ULL;
        unsigned k = TOPK;
        for (int pass = 7; pass >= 0; --pass) {
            if (tid < 256) hist[tid] = 0u;
            __syncthreads();
            const int shift = pass * 8;
            const unsigned long long prefmask =
                (pass == 7) ? 0ULL : (0xFFFFFFFFFFFFFFFFULL << (shift + 8));
            for (int i = tid; i < NANCH; i += 1024) {
                unsigned u = __float_as_uint(S[i]);
                unsigned long long key = ((unsigned long long)u << 32)
                                       | (unsigned long long)(0xFFFFFFFFu - (unsigned)i);
                if ((key & prefmask) == prefix)
                    atomicAdd(&hist[(unsigned)((key >> shift) & 0xFFULL)], 1u);
            }
            __syncthreads();
            if (tid == 0) {
                unsigned cum = 0; int d = 0;
                for (int v = 255; v >= 0; --v) {
                    unsigned c = hist[v];
                    if (cum + c >= k) { d = v; break; }
                    cum += c;
                }
                sh_d = (unsigned)d;
                sh_k2 = k - cum;
            }
            __syncthreads();
            prefix |= ((unsigned long long)sh_d) << shift;
            k = sh_k2;
            __syncthreads();
        }
        if (tid == 0) wcnt = 0u;
        __syncthreads();
        for (int i = tid; i < NANCH; i += 1024) {
            unsigned u = __float_as_uint(S[i]);
            unsigned long long key = ((unsigned long long)u << 32)
                                   | (unsigned long long)(0xFFFFFFFFu - (unsigned)i);
            if (key >= prefix) {
                unsigned pos = atomicAdd(&wcnt, 1u);
                wbuf[pos] = key;
            }
        }
        __syncthreads();
        const int m = (int)wcnt;   // == TOPK
        if (tid < m) {
            unsigned long long my = wbuf[tid];
            int r = 0;
            for (int j = 0; j < m; ++j) r += (wbuf[j] > my) ? 1 : 0;
            keep[b * TOPK + r] = (int)(0xFFFFFFFFu - (unsigned)(my & 0xFFFFFFFFULL));
        }
    }
}

// ------------- Kernel 3: gather + decode kept rows -----------------------------------------
__global__ void emit_kernel(const int* __restrict__ keep,
                            const float* __restrict__ S,
                            const float* __restrict__ bbox0, const float* __restrict__ bbox1,
                            const float* __restrict__ bbox2,
                            const float* __restrict__ kpt0, const float* __restrict__ kpt1,
                            const float* __restrict__ kpt2,
                            const float* __restrict__ vis0, const float* __restrict__ vis1,
                            const float* __restrict__ vis2,
                            float* __restrict__ out) {
    int gid = blockIdx.x * blockDim.x + threadIdx.x;
    const int total = BATCH * TOPK * 18;
    if (gid >= total) return;
    int slot = gid % 18;
    int br   = gid / 18;
    int r = br % TOPK;
    int b = br / TOPK;
    int n = keep[b * TOPK + r];

    int nl, W, HW; float s;
    const float *bb, *kp, *vp;
    if (n < N0) {
        nl = n;            W = 160; HW = N0; s = 8.f;
        bb = bbox0; kp = kpt0; vp = vis0;
    } else if (n < N0 + N1) {
        nl = n - N0;       W = 80;  HW = N1; s = 16.f;
        bb = bbox1; kp = kpt1; vp = vis1;
    } else {
        nl = n - N0 - N1;  W = 40;  HW = N2; s = 32.f;
        bb = bbox2; kp = kpt2; vp = vis2;
    }
    float px = (float)(nl % W) * s;
    float py = (float)(nl / W) * s;

    if (slot == 17) {
        float bx = bb[((size_t)b * 4 + 0) * HW + nl];
        float by = bb[((size_t)b * 4 + 1) * HW + nl];
        float bw = bb[((size_t)b * 4 + 2) * HW + nl];
        float bh = bb[((size_t)b * 4 + 3) * HW + nl];
        float score = S[(size_t)b * NANCH + n];
        float cx = bx * s + px;
        float cy = by * s + py;
        float hw_ = expf(bw) * s * 0.5f;
        float hh  = expf(bh) * s * 0.5f;
        float* o = out + ((size_t)b * TOPK + r) * 5;
        o[0] = cx - hw_;
        o[1] = cy - hh;
        o[2] = cx + hw_;
        o[3] = cy + hh;
        o[4] = score;
    } else {
        int kk = slot;
        float xk = kp[((size_t)b * 34 + 2 * kk    ) * HW + nl];
        float yk = kp[((size_t)b * 34 + 2 * kk + 1) * HW + nl];
        float vv = vp[((size_t)b * 17 + kk        ) * HW + nl];
        float* o = out + (size_t)(BATCH * TOPK * 5) + (((size_t)b * TOPK + r) * 17 + kk) * 3;
        o[0] = xk * s + px;
        o[1] = yk * s + py;
        o[2] = sigmoid_np(vv);
    }
}

extern "C" void kernel_launch(void* const* d_in, const int* in_sizes, int n_in,
                              void* d_out, int out_size, void* d_ws, size_t ws_size,
                              hipStream_t stream) {
    const float* cls0  = (const float*)d_in[0];
    const float* cls1  = (const float*)d_in[1];
    const float* cls2  = (const float*)d_in[2];
    const float* bbox0 = (const float*)d_in[3];
    const float* bbox1 = (const float*)d_in[4];
    const float* bbox2 = (const float*)d_in[5];
    const float* obj0  = (const float*)d_in[6];
    const float* obj1  = (const float*)d_in[7];
    const float* obj2  = (const float*)d_in[8];
    const float* kpt0  = (const float*)d_in[9];
    const float* kpt1  = (const float*)d_in[10];
    const float* kpt2  = (const float*)d_in[11];
    const float* vis0  = (const float*)d_in[12];
    const float* vis1  = (const float*)d_in[13];
    const float* vis2  = (const float*)d_in[14];
    float* out = (float*)d_out;

    float* S  = (float*)d_ws;
    int* keep = (int*)((char*)d_ws + (size_t)BATCH * NANCH * sizeof(float));

    dim3 g1((NANCH + 255) / 256, BATCH);
    score_kernel<<<g1, 256, 0, stream>>>(cls0, cls1, cls2, obj0, obj1, obj2, S);

    select_kernel<<<BATCH, 1024, 0, stream>>>(S, keep);

    const int total = BATCH * TOPK * 18;
    emit_kernel<<<(total + 255) / 256, 256, 0, stream>>>(keep, S,
        bbox0, bbox1, bbox2, kpt0, kpt1, kpt2, vis0, vis1, vis2, out);
}